// Round 1
// baseline (430.862 us; speedup 1.0000x reference)
//
#include <hip/hip_runtime.h>
#include <math.h>

#define BSZ 8
#define KG  8
#define NP  16
#define MM  64            // BS*K
#define TT  3072
#define WGN 64
#define HH  256
#define WCN 256
#define RHN 1024
#define RWN 512

#define C1H 1024
#define C1W 31
#define C2H 341
#define C2W 15
#define C3H 113
#define C3W 7

#define N_GATHER (MM*TT*WGN)          // 12,582,912
#define N1 (MM*C1H*C1W)               // 2,031,616
#define N2 (MM*C2H*C2W)               // 327,360 (per channel)
#define N3 (MM*C3H*C3W)               // 50,624
#define NF (BSZ*RHN*RWN)              // 4,194,304

// ---- workspace byte offsets ----
// [0,80)    : double sums[10]  {s1,ss1, s2c0,ss2c0, s2c1,ss2c1, s3,ss3, sf,ssf}
// [120,124) : uint absmax
// [128,168) : float scal[10]   {a1,b1, a2c0,b2c0, a2c1,b2c1, a3,b3, af,bf}
// [256,...) : vint (64*256 int), y1 (N1 f), mp3 (N1 f), mp5 (N1 f),
//             y2 (2*N2 f), y3 (N3 f), genr (64*1024 f), mix (NF f)
#define OFF_AMAX 120
#define OFF_SCAL 128
#define OFF_VINT 256
#define OFF_Y1   (OFF_VINT + MM*HH*4)
#define OFF_MP3  (OFF_Y1  + N1*4)
#define OFF_MP5  (OFF_MP3 + N1*4)
#define OFF_Y2   (OFF_MP5 + N1*4)
#define OFF_Y3   (OFF_Y2  + 2*N2*4)
#define OFF_GENR (OFF_Y3  + N3*4)
#define OFF_MIX  (OFF_GENR + MM*RHN*4)

__device__ __forceinline__ void blockAdd2(double s, double ss, double* o0, double* o1) {
    __shared__ double red[4][2];
    __syncthreads();                       // protect reuse across sequential calls
    int lane = threadIdx.x & 63, wid = threadIdx.x >> 6;
#pragma unroll
    for (int off = 32; off > 0; off >>= 1) {
        s  += __shfl_down(s,  off, 64);
        ss += __shfl_down(ss, off, 64);
    }
    if (lane == 0) { red[wid][0] = s; red[wid][1] = ss; }
    __syncthreads();
    if (threadIdx.x == 0) {
        double a = 0, b = 0;
        int nw = blockDim.x >> 6;
        for (int i = 0; i < nw; i++) { a += red[i][0]; b += red[i][1]; }
        atomicAdd(o0, a); atomicAdd(o1, b);
    }
}

// ---- K1: global absmax of gather ----
__global__ void k_absmax(const float* __restrict__ g, unsigned int* amax) {
    int tid = blockIdx.x * blockDim.x + threadIdx.x;
    int stride = gridDim.x * blockDim.x;
    const float4* g4 = (const float4*)g;
    float m = 0.f;
    for (int i = tid; i < N_GATHER / 4; i += stride) {
        float4 v = g4[i];
        m = fmaxf(m, fmaxf(fmaxf(fabsf(v.x), fabsf(v.y)), fmaxf(fabsf(v.z), fabsf(v.w))));
    }
#pragma unroll
    for (int off = 32; off > 0; off >>= 1) m = fmaxf(m, __shfl_down(m, off, 64));
    if ((threadIdx.x & 63) == 0) atomicMax(amax, __float_as_uint(m));
}

// ---- K2: conv1 (1x1x3x3, stride 3x2, VALID) with /absmax folded in; BN1 stats ----
__global__ void k_conv1(const float* __restrict__ g, const float* __restrict__ w1,
                        const float* __restrict__ b1, const unsigned int* __restrict__ amax,
                        float* __restrict__ y1, double* sums) {
    float inv = 1.0f / __uint_as_float(*amax);
    float w[9];
#pragma unroll
    for (int i = 0; i < 9; i++) w[i] = w1[i] * inv;
    float bb = b1[0];
    double s = 0, ss = 0;
    int stride = gridDim.x * blockDim.x;
    for (int idx = blockIdx.x * blockDim.x + threadIdx.x; idx < N1; idx += stride) {
        int ow = idx % C1W;
        int t2 = idx / C1W;
        int oh = t2 % C1H;
        int m  = t2 / C1H;
        const float* xp = g + (size_t)m * TT * WGN + (size_t)(oh * 3) * WGN + ow * 2;
        float acc = bb;
#pragma unroll
        for (int r = 0; r < 3; r++)
#pragma unroll
            for (int c = 0; c < 3; c++) acc += w[r * 3 + c] * xp[r * WGN + c];
        y1[idx] = acc;
        s += acc; ss += (double)acc * (double)acc;
    }
    blockAdd2(s, ss, &sums[0], &sums[1]);
}

// ---- BN finalize: a = g/sqrt(var+eps); b = beta - mean*a ----
__global__ void k_bnfin(const double* __restrict__ s, const float* __restrict__ g,
                        const float* __restrict__ be, float* __restrict__ ab,
                        int nch, double n) {
    int c = threadIdx.x;
    if (c < nch) {
        double mean = s[2 * c] / n;
        double var  = s[2 * c + 1] / n - mean * mean;
        double a = (double)g[c] / sqrt(var + 1e-5);
        ab[2 * c]     = (float)a;
        ab[2 * c + 1] = (float)((double)be[c] - mean * a);
    }
}

// ---- generic in-place affine + LReLU ----
__global__ void k_act(float* __restrict__ x, const float* __restrict__ ab, int n) {
    int i = blockIdx.x * blockDim.x + threadIdx.x;
    if (i < n) {
        float v = ab[0] * x[i] + ab[1];
        x[i] = v >= 0.f ? v : 0.1f * v;
    }
}

// ---- K5: maxpool3 & maxpool5 (stride 1, -inf pad) of activated y1 ----
__global__ void k_pools(const float* __restrict__ act, float* __restrict__ mp3,
                        float* __restrict__ mp5) {
    int idx = blockIdx.x * blockDim.x + threadIdx.x;
    if (idx >= N1) return;
    int w  = idx % C1W;
    int t2 = idx / C1W;
    int h  = t2 % C1H;
    int m  = t2 / C1H;
    const float* p = act + (size_t)m * C1H * C1W;
    float m3 = -INFINITY, m5 = -INFINITY;
#pragma unroll
    for (int dh = -2; dh <= 2; dh++) {
        int hh = h + dh;
        if (hh < 0 || hh >= C1H) continue;
#pragma unroll
        for (int dw = -2; dw <= 2; dw++) {
            int ww = w + dw;
            if (ww < 0 || ww >= C1W) continue;
            float v = p[hh * C1W + ww];
            m5 = fmaxf(m5, v);
            if (dh >= -1 && dh <= 1 && dw >= -1 && dw <= 1) m3 = fmaxf(m3, v);
        }
    }
    mp3[idx] = m3;
    mp5[idx] = m5;
}

// ---- K6: conv2 (2x3x3x3, stride 3x2) over [act,mp3,mp5]; BN2 stats per channel ----
__global__ void k_conv2(const float* __restrict__ act, const float* __restrict__ mp3,
                        const float* __restrict__ mp5, const float* __restrict__ w2,
                        const float* __restrict__ b2, float* __restrict__ y2, double* sums) {
    double s0 = 0, ss0 = 0, s1 = 0, ss1 = 0;
    int stride = gridDim.x * blockDim.x;
    for (int idx = blockIdx.x * blockDim.x + threadIdx.x; idx < N2; idx += stride) {
        int ow = idx % C2W;
        int t2 = idx / C2W;
        int oh = t2 % C2H;
        int m  = t2 / C2H;
        size_t base = (size_t)m * C1H * C1W + (size_t)(oh * 3) * C1W + ow * 2;
        const float* ch[3] = { act + base, mp3 + base, mp5 + base };
        float a0 = b2[0], a1 = b2[1];
#pragma unroll
        for (int i = 0; i < 3; i++)
#pragma unroll
            for (int r = 0; r < 3; r++)
#pragma unroll
                for (int c = 0; c < 3; c++) {
                    float v = ch[i][r * C1W + c];
                    a0 += w2[i * 9 + r * 3 + c] * v;
                    a1 += w2[27 + i * 9 + r * 3 + c] * v;
                }
        size_t ob = (size_t)m * (2 * C2H * C2W) + (size_t)oh * C2W + ow;
        y2[ob] = a0;
        y2[ob + C2H * C2W] = a1;
        s0 += a0; ss0 += (double)a0 * a0;
        s1 += a1; ss1 += (double)a1 * a1;
    }
    blockAdd2(s0, ss0, &sums[2], &sums[3]);
    blockAdd2(s1, ss1, &sums[4], &sums[5]);
}

// ---- K8: conv3 (1x2x3x2, stride 3x2), BN2 affine+LReLU applied on the fly; BN3 stats ----
__global__ void k_conv3(const float* __restrict__ y2, const float* __restrict__ scal,
                        const float* __restrict__ w3, const float* __restrict__ b3,
                        float* __restrict__ y3, double* sums) {
    double s = 0, ss = 0;
    float a20 = scal[2], b20 = scal[3], a21 = scal[4], b21 = scal[5];
    int stride = gridDim.x * blockDim.x;
    for (int idx = blockIdx.x * blockDim.x + threadIdx.x; idx < N3; idx += stride) {
        int ow = idx % C3W;
        int t2 = idx / C3W;
        int oh = t2 % C3H;
        int m  = t2 / C3H;
        float acc = b3[0];
#pragma unroll
        for (int i = 0; i < 2; i++) {
            float aa = i ? a21 : a20, bb = i ? b21 : b20;
            const float* cp = y2 + (size_t)m * (2 * C2H * C2W) + (size_t)i * C2H * C2W
                              + (size_t)(oh * 3) * C2W + ow * 2;
#pragma unroll
            for (int r = 0; r < 3; r++)
#pragma unroll
                for (int c = 0; c < 2; c++) {
                    float v = aa * cp[r * C2W + c] + bb;
                    v = v >= 0.f ? v : 0.1f * v;
                    acc += w3[i * 6 + r * 2 + c] * v;
                }
        }
        y3[idx] = acc;
        s += acc; ss += (double)acc * acc;
    }
    blockAdd2(s, ss, &sums[6], &sums[7]);
}

// ---- K10: per-curve interp -> v_int[m][h] ----
__global__ void k_vint(const float* __restrict__ cv, const float* __restrict__ VMM,
                       int* __restrict__ vint) {
    __shared__ float tt[NP], vv[NP];
    int m = blockIdx.x;
    int b = m >> 3;
    if (threadIdx.x < NP) {
        int n = threadIdx.x;
        float t = cv[(m * NP + n) * 2 + 0];
        float v = cv[(m * NP + n) * 2 + 1];
        float dt = 7000.0f / 255.0f;
        tt[n] = t / dt;
        float vmin = VMM[b * 2], vmax = VMM[b * 2 + 1];
        float dv = (vmax - vmin) / 255.0f;
        vv[n] = (v - vmin) / dv;
    }
    __syncthreads();
    int h = threadIdx.x;
    float x = (float)h;
    float val;
    if (x <= tt[0]) val = vv[0];
    else if (x >= tt[NP - 1]) val = vv[NP - 1];
    else {
        int i = 1;
        while (i < NP - 1 && tt[i] <= x) i++;
        float d = tt[i] - tt[i - 1];
        val = (d != 0.f) ? vv[i - 1] + (x - tt[i - 1]) / d * (vv[i] - vv[i - 1]) : vv[i];
    }
    int vi = (int)val;
    vi = max(0, min(WCN - 1, vi));
    vint[m * HH + h] = vi;
}

// ---- K11: BN3 affine+LReLU, then resize (113,7)->(1024,1) ----
// W: antialiased downsample to 1 col, fixed weights [4,5,6,7,6,5,4]/37 at x=3.0
// H: half-pixel linear upsample with edge clamp
__global__ void k_genr(const float* __restrict__ y3, const float* __restrict__ scal,
                       float* __restrict__ genr) {
    __shared__ float tile[C3H * C3W];
    int m = blockIdx.x;
    float a = scal[6], b = scal[7];
    for (int i = threadIdx.x; i < C3H * C3W; i += blockDim.x) {
        float v = a * y3[m * C3H * C3W + i] + b;
        tile[i] = v >= 0.f ? v : 0.1f * v;
    }
    __syncthreads();
    const float cw0 = 4.f / 37.f, cw1 = 5.f / 37.f, cw2 = 6.f / 37.f, cw3 = 7.f / 37.f;
    const float cw[7] = { cw0, cw1, cw2, cw3, cw2, cw1, cw0 };
    for (int i = threadIdx.x; i < RHN; i += blockDim.x) {
        float sh = (i + 0.5f) * (113.0f / 1024.0f) - 0.5f;
        float fl = floorf(sh);
        float fr = sh - fl;
        int i0 = (int)fl, i1 = i0 + 1;
        i0 = max(0, min(C3H - 1, i0));
        i1 = max(0, min(C3H - 1, i1));
        float acc = 0.f;
#pragma unroll
        for (int x = 0; x < 7; x++) {
            float v = (1.f - fr) * tile[i0 * C3W + x] + fr * tile[i1 * C3W + x];
            acc += cw[x] * v;
        }
        genr[m * RHN + i] = acc;
    }
}

// ---- K12: mix = sum_k genr * resized_mask, mask resize fused on the fly ----
__global__ void k_mix(const float* __restrict__ genr, const int* __restrict__ vint,
                      float* __restrict__ mix) {
    int bh = blockIdx.x;
    int h = bh % RHN, b = bh / RHN;
    __shared__ float g[KG];
    __shared__ int v0[KG], v1[KG];
    float sh = (h + 0.5f) * 0.25f - 0.5f;
    float fl = floorf(sh);
    float fh = sh - fl;
    int ih0 = (int)fl, ih1 = ih0 + 1;
    ih0 = max(0, min(HH - 1, ih0));
    ih1 = max(0, min(HH - 1, ih1));
    if (threadIdx.x < KG) {
        int k = threadIdx.x;
        int m = b * KG + k;
        g[k]  = genr[m * RHN + h];
        v0[k] = vint[m * HH + ih0];
        v1[k] = vint[m * HH + ih1];
    }
    __syncthreads();
    float G = 0.f;
#pragma unroll
    for (int k = 0; k < KG; k++) G += g[k];
    for (int w = threadIdx.x; w < RWN; w += blockDim.x) {
        float sw = (w + 0.5f) * 0.5f - 0.5f;
        float flw = floorf(sw);
        float fw = sw - flw;
        int iw0 = (int)flw, iw1 = iw0 + 1;
        iw0 = max(0, min(WCN - 1, iw0));
        iw1 = max(0, min(WCN - 1, iw1));
        float S = 0.f;
#pragma unroll
        for (int k = 0; k < KG; k++) {
            float b0 = ((iw0 == v0[k]) ? (1.f - fw) : 0.f) + ((iw1 == v0[k]) ? fw : 0.f);
            float b1 = ((iw0 == v1[k]) ? (1.f - fw) : 0.f) + ((iw1 == v1[k]) ? fw : 0.f);
            S += g[k] * ((1.f - fh) * b0 + fh * b1);
        }
        mix[((size_t)b * RHN + h) * RWN + w] = 0.01f * G + 0.9f * S;
    }
}

// ---- K13: final conv 3x3 pad 1 over mix; BNf stats; writes raw conv to out ----
__global__ void k_convf(const float* __restrict__ mix, const float* __restrict__ wf,
                        const float* __restrict__ bf, float* __restrict__ out, double* sums) {
    double s = 0, ss = 0;
    float w[9];
#pragma unroll
    for (int i = 0; i < 9; i++) w[i] = wf[i];
    float bb = bf[0];
    int stride = gridDim.x * blockDim.x;
    for (int idx = blockIdx.x * blockDim.x + threadIdx.x; idx < NF; idx += stride) {
        int x  = idx % RWN;
        int t2 = idx / RWN;
        int y  = t2 % RHN;
        int b  = t2 / RHN;
        const float* p = mix + (size_t)b * RHN * RWN;
        float acc = bb;
#pragma unroll
        for (int r = 0; r < 3; r++) {
            int hh = y - 1 + r;
            if (hh < 0 || hh >= RHN) continue;
#pragma unroll
            for (int c = 0; c < 3; c++) {
                int ww = x - 1 + c;
                if (ww < 0 || ww >= RWN) continue;
                acc += w[r * 3 + c] * p[(size_t)hh * RWN + ww];
            }
        }
        out[idx] = acc;
        s += acc; ss += (double)acc * acc;
    }
    blockAdd2(s, ss, &sums[8], &sums[9]);
}

extern "C" void kernel_launch(void* const* d_in, const int* in_sizes, int n_in,
                              void* d_out, int out_size, void* d_ws, size_t ws_size,
                              hipStream_t stream) {
    const float* gather = (const float*)d_in[0];
    const float* cv     = (const float*)d_in[1];
    const float* VMM    = (const float*)d_in[2];
    const float* w1 = (const float*)d_in[3];
    const float* b1 = (const float*)d_in[4];
    const float* g1 = (const float*)d_in[5];
    const float* be1 = (const float*)d_in[6];
    const float* w2 = (const float*)d_in[7];
    const float* b2 = (const float*)d_in[8];
    const float* g2 = (const float*)d_in[9];
    const float* be2 = (const float*)d_in[10];
    const float* w3 = (const float*)d_in[11];
    const float* b3 = (const float*)d_in[12];
    const float* g3 = (const float*)d_in[13];
    const float* be3 = (const float*)d_in[14];
    const float* wf = (const float*)d_in[15];
    const float* bf = (const float*)d_in[16];
    const float* gf = (const float*)d_in[17];
    const float* bef = (const float*)d_in[18];
    float* out = (float*)d_out;

    char* ws = (char*)d_ws;
    double* sums        = (double*)ws;
    unsigned int* amax  = (unsigned int*)(ws + OFF_AMAX);
    float* scal         = (float*)(ws + OFF_SCAL);
    int*   vint         = (int*)(ws + OFF_VINT);
    float* y1           = (float*)(ws + OFF_Y1);
    float* mp3          = (float*)(ws + OFF_MP3);
    float* mp5          = (float*)(ws + OFF_MP5);
    float* y2           = (float*)(ws + OFF_Y2);
    float* y3           = (float*)(ws + OFF_Y3);
    float* genr         = (float*)(ws + OFF_GENR);
    float* mix          = (float*)(ws + OFF_MIX);

    hipMemsetAsync(d_ws, 0, 256, stream);

    k_absmax<<<2048, 256, 0, stream>>>(gather, amax);
    k_conv1<<<1024, 256, 0, stream>>>(gather, w1, b1, amax, y1, sums);
    k_bnfin<<<1, 64, 0, stream>>>(sums + 0, g1, be1, scal + 0, 1, (double)N1);
    k_act<<<(N1 + 255) / 256, 256, 0, stream>>>(y1, scal + 0, N1);
    k_pools<<<(N1 + 255) / 256, 256, 0, stream>>>(y1, mp3, mp5);
    k_conv2<<<640, 256, 0, stream>>>(y1, mp3, mp5, w2, b2, y2, sums);
    k_bnfin<<<1, 64, 0, stream>>>(sums + 2, g2, be2, scal + 2, 2, (double)N2);
    k_conv3<<<198, 256, 0, stream>>>(y2, scal, w3, b3, y3, sums);
    k_bnfin<<<1, 64, 0, stream>>>(sums + 6, g3, be3, scal + 6, 1, (double)N3);
    k_vint<<<MM, 256, 0, stream>>>(cv, VMM, vint);
    k_genr<<<MM, 256, 0, stream>>>(y3, scal, genr);
    k_mix<<<BSZ * RHN, 256, 0, stream>>>(genr, vint, mix);
    k_convf<<<2048, 256, 0, stream>>>(mix, wf, bf, out, sums);
    k_bnfin<<<1, 64, 0, stream>>>(sums + 8, gf, bef, scal + 8, 1, (double)NF);
    k_act<<<(NF + 255) / 256, 256, 0, stream>>>(out, scal + 8, NF);
}

// Round 2
// 276.168 us; speedup vs baseline: 1.5601x; 1.5601x over previous
//
#include <hip/hip_runtime.h>
#include <math.h>

#define BSZ 8
#define KG  8
#define NP  16
#define MM  64            // BS*K
#define TT  3072
#define WGN 64
#define HH  256
#define WCN 256
#define RHN 1024
#define RWN 512

#define C1H 1024
#define C1W 31
#define C2H 341
#define C2W 15
#define C3H 113
#define C3W 7

#define N_GATHER (MM*TT*WGN)          // 12,582,912
#define N1 (MM*C1H*C1W)               // 2,031,616
#define N2 (MM*C2H*C2W)               // 327,360 (per channel)
#define N3 (MM*C3H*C3W)               // 50,624
#define NF (BSZ*RHN*RWN)              // 4,194,304

#define SL 8   // atomic spread slots

// ---- workspace byte offsets ----
// [0,640)   : double sums[10][SL]  counter-major: {s1,ss1, s2c0,ss2c0, s2c1,ss2c1, s3,ss3, sf,ssf}
// [640,672) : uint absmax[SL]
// [672,712) : float scal[10]   {a1,b1, a2c0,b2c0, a2c1,b2c1, a3,b3, af,bf}
// [768,...) : vint (64*256 int), y1 (N1 f), mp3 (N1 f), mp5 (N1 f),
//             y2 (2*N2 f), y3 (N3 f), genr (64*1024 f), mix (NF f)
// act buffer (N1 f) ALIASES the mix region: act is dead before k_mix writes.
#define OFF_AMAX 640
#define OFF_SCAL 672
#define OFF_VINT 768
#define OFF_Y1   (OFF_VINT + MM*HH*4)
#define OFF_MP3  (OFF_Y1  + N1*4)
#define OFF_MP5  (OFF_MP3 + N1*4)
#define OFF_Y2   (OFF_MP5 + N1*4)
#define OFF_Y3   (OFF_Y2  + 2*N2*4)
#define OFF_GENR (OFF_Y3  + N3*4)
#define OFF_MIX  (OFF_GENR + MM*RHN*4)
#define OFF_ACT  OFF_MIX   // alias: act dead before mix written

__device__ __forceinline__ void blockAdd2(double s, double ss, double* o0, double* o1) {
    __shared__ double red[4][2];
    __syncthreads();                       // protect reuse across sequential calls
    int lane = threadIdx.x & 63, wid = threadIdx.x >> 6;
#pragma unroll
    for (int off = 32; off > 0; off >>= 1) {
        s  += __shfl_down(s,  off, 64);
        ss += __shfl_down(ss, off, 64);
    }
    if (lane == 0) { red[wid][0] = s; red[wid][1] = ss; }
    __syncthreads();
    if (threadIdx.x == 0) {
        double a = 0, b = 0;
        int nw = blockDim.x >> 6;
        for (int i = 0; i < nw; i++) { a += red[i][0]; b += red[i][1]; }
        int slot = blockIdx.x & (SL - 1);
        atomicAdd(&o0[slot], a); atomicAdd(&o1[slot], b);
    }
}

// ---- K1: global absmax of gather; 1 atomic per block, spread over SL slots ----
__global__ void k_absmax(const float* __restrict__ g, unsigned int* amax) {
    __shared__ float red[4];
    int tid = blockIdx.x * blockDim.x + threadIdx.x;
    int stride = gridDim.x * blockDim.x;
    const float4* g4 = (const float4*)g;
    float m = 0.f;
    for (int i = tid; i < N_GATHER / 4; i += stride) {
        float4 v = g4[i];
        m = fmaxf(m, fmaxf(fmaxf(fabsf(v.x), fabsf(v.y)), fmaxf(fabsf(v.z), fabsf(v.w))));
    }
#pragma unroll
    for (int off = 32; off > 0; off >>= 1) m = fmaxf(m, __shfl_down(m, off, 64));
    int lane = threadIdx.x & 63, wid = threadIdx.x >> 6;
    if (lane == 0) red[wid] = m;
    __syncthreads();
    if (threadIdx.x == 0) {
        float mm = fmaxf(fmaxf(red[0], red[1]), fmaxf(red[2], red[3]));
        atomicMax(&amax[blockIdx.x & (SL - 1)], __float_as_uint(mm));
    }
}

// ---- K2: conv1 (1x1x3x3, stride 3x2, VALID) with /absmax folded in; BN1 stats ----
__global__ void k_conv1(const float* __restrict__ g, const float* __restrict__ w1,
                        const float* __restrict__ b1, const unsigned int* __restrict__ amax,
                        float* __restrict__ y1, double* sums) {
    float mx = 0.f;
#pragma unroll
    for (int i = 0; i < SL; i++) mx = fmaxf(mx, __uint_as_float(amax[i]));
    float inv = 1.0f / mx;
    float w[9];
#pragma unroll
    for (int i = 0; i < 9; i++) w[i] = w1[i] * inv;
    float bb = b1[0];
    double s = 0, ss = 0;
    int stride = gridDim.x * blockDim.x;
    for (int idx = blockIdx.x * blockDim.x + threadIdx.x; idx < N1; idx += stride) {
        int ow = idx % C1W;
        int t2 = idx / C1W;
        int oh = t2 % C1H;
        int m  = t2 / C1H;
        const float* xp = g + (size_t)m * TT * WGN + (size_t)(oh * 3) * WGN + ow * 2;
        float acc = bb;
#pragma unroll
        for (int r = 0; r < 3; r++)
#pragma unroll
            for (int c = 0; c < 3; c++) acc += w[r * 3 + c] * xp[r * WGN + c];
        y1[idx] = acc;
        s += acc; ss += (double)acc * (double)acc;
    }
    blockAdd2(s, ss, &sums[0], &sums[SL]);
}

// ---- BN finalize: a = g/sqrt(var+eps); b = beta - mean*a. s = 8-slot counters ----
__global__ void k_bnfin(const double* __restrict__ s, const float* __restrict__ g,
                        const float* __restrict__ be, float* __restrict__ ab,
                        int nch, double n) {
    int c = threadIdx.x;
    if (c < nch) {
        double sum = 0, sumsq = 0;
        for (int j = 0; j < SL; j++) {
            sum   += s[(2 * c) * SL + j];
            sumsq += s[(2 * c + 1) * SL + j];
        }
        double mean = sum / n;
        double var  = sumsq / n - mean * mean;
        double a = (double)g[c] / sqrt(var + 1e-5);
        ab[2 * c]     = (float)a;
        ab[2 * c + 1] = (float)((double)be[c] - mean * a);
    }
}

// ---- K4: fused BN1-affine+LReLU + maxpool3 + maxpool5 (act computed on the fly) ----
__global__ void k_actpools(const float* __restrict__ y1raw, const float* __restrict__ scal,
                           float* __restrict__ act, float* __restrict__ mp3,
                           float* __restrict__ mp5) {
    int idx = blockIdx.x * blockDim.x + threadIdx.x;
    if (idx >= N1) return;
    float a = scal[0], b = scal[1];
    int w  = idx % C1W;
    int t2 = idx / C1W;
    int h  = t2 % C1H;
    int m  = t2 / C1H;
    const float* p = y1raw + (size_t)m * C1H * C1W;
    float m3 = -INFINITY, m5 = -INFINITY;
#pragma unroll
    for (int dh = -2; dh <= 2; dh++) {
        int hh = h + dh;
        if (hh < 0 || hh >= C1H) continue;
#pragma unroll
        for (int dw = -2; dw <= 2; dw++) {
            int ww = w + dw;
            if (ww < 0 || ww >= C1W) continue;
            float v = a * p[hh * C1W + ww] + b;
            v = v >= 0.f ? v : 0.1f * v;
            m5 = fmaxf(m5, v);
            if (dh >= -1 && dh <= 1 && dw >= -1 && dw <= 1) m3 = fmaxf(m3, v);
        }
    }
    float cvv = a * p[h * C1W + w] + b;
    cvv = cvv >= 0.f ? cvv : 0.1f * cvv;
    act[idx] = cvv;
    mp3[idx] = m3;
    mp5[idx] = m5;
}

// ---- K5: conv2 (2x3x3x3, stride 3x2) over [act,mp3,mp5]; BN2 stats per channel ----
__global__ void k_conv2(const float* __restrict__ act, const float* __restrict__ mp3,
                        const float* __restrict__ mp5, const float* __restrict__ w2,
                        const float* __restrict__ b2, float* __restrict__ y2, double* sums) {
    double s0 = 0, ss0 = 0, s1 = 0, ss1 = 0;
    int stride = gridDim.x * blockDim.x;
    for (int idx = blockIdx.x * blockDim.x + threadIdx.x; idx < N2; idx += stride) {
        int ow = idx % C2W;
        int t2 = idx / C2W;
        int oh = t2 % C2H;
        int m  = t2 / C2H;
        size_t base = (size_t)m * C1H * C1W + (size_t)(oh * 3) * C1W + ow * 2;
        const float* ch[3] = { act + base, mp3 + base, mp5 + base };
        float a0 = b2[0], a1 = b2[1];
#pragma unroll
        for (int i = 0; i < 3; i++)
#pragma unroll
            for (int r = 0; r < 3; r++)
#pragma unroll
                for (int c = 0; c < 3; c++) {
                    float v = ch[i][r * C1W + c];
                    a0 += w2[i * 9 + r * 3 + c] * v;
                    a1 += w2[27 + i * 9 + r * 3 + c] * v;
                }
        size_t ob = (size_t)m * (2 * C2H * C2W) + (size_t)oh * C2W + ow;
        y2[ob] = a0;
        y2[ob + C2H * C2W] = a1;
        s0 += a0; ss0 += (double)a0 * a0;
        s1 += a1; ss1 += (double)a1 * a1;
    }
    blockAdd2(s0, ss0, &sums[2 * SL], &sums[3 * SL]);
    blockAdd2(s1, ss1, &sums[4 * SL], &sums[5 * SL]);
}

// ---- K7: conv3 (1x2x3x2, stride 3x2), BN2 affine+LReLU applied on the fly; BN3 stats ----
__global__ void k_conv3(const float* __restrict__ y2, const float* __restrict__ scal,
                        const float* __restrict__ w3, const float* __restrict__ b3,
                        float* __restrict__ y3, double* sums) {
    double s = 0, ss = 0;
    float a20 = scal[2], b20 = scal[3], a21 = scal[4], b21 = scal[5];
    int stride = gridDim.x * blockDim.x;
    for (int idx = blockIdx.x * blockDim.x + threadIdx.x; idx < N3; idx += stride) {
        int ow = idx % C3W;
        int t2 = idx / C3W;
        int oh = t2 % C3H;
        int m  = t2 / C3H;
        float acc = b3[0];
#pragma unroll
        for (int i = 0; i < 2; i++) {
            float aa = i ? a21 : a20, bb = i ? b21 : b20;
            const float* cp = y2 + (size_t)m * (2 * C2H * C2W) + (size_t)i * C2H * C2W
                              + (size_t)(oh * 3) * C2W + ow * 2;
#pragma unroll
            for (int r = 0; r < 3; r++)
#pragma unroll
                for (int c = 0; c < 2; c++) {
                    float v = aa * cp[r * C2W + c] + bb;
                    v = v >= 0.f ? v : 0.1f * v;
                    acc += w3[i * 6 + r * 2 + c] * v;
                }
        }
        y3[idx] = acc;
        s += acc; ss += (double)acc * acc;
    }
    blockAdd2(s, ss, &sums[6 * SL], &sums[7 * SL]);
}

// ---- K9: per-curve interp -> v_int[m][h] ----
__global__ void k_vint(const float* __restrict__ cv, const float* __restrict__ VMM,
                       int* __restrict__ vint) {
    __shared__ float tt[NP], vv[NP];
    int m = blockIdx.x;
    int b = m >> 3;
    if (threadIdx.x < NP) {
        int n = threadIdx.x;
        float t = cv[(m * NP + n) * 2 + 0];
        float v = cv[(m * NP + n) * 2 + 1];
        float dt = 7000.0f / 255.0f;
        tt[n] = t / dt;
        float vmin = VMM[b * 2], vmax = VMM[b * 2 + 1];
        float dv = (vmax - vmin) / 255.0f;
        vv[n] = (v - vmin) / dv;
    }
    __syncthreads();
    int h = threadIdx.x;
    float x = (float)h;
    float val;
    if (x <= tt[0]) val = vv[0];
    else if (x >= tt[NP - 1]) val = vv[NP - 1];
    else {
        int i = 1;
        while (i < NP - 1 && tt[i] <= x) i++;
        float d = tt[i] - tt[i - 1];
        val = (d != 0.f) ? vv[i - 1] + (x - tt[i - 1]) / d * (vv[i] - vv[i - 1]) : vv[i];
    }
    int vi = (int)val;
    vi = max(0, min(WCN - 1, vi));
    vint[m * HH + h] = vi;
}

// ---- K10: BN3 affine+LReLU, then resize (113,7)->(1024,1) ----
// W: antialiased downsample to 1 col, fixed weights [4,5,6,7,6,5,4]/37 at x=3.0
// H: half-pixel linear upsample with edge clamp
__global__ void k_genr(const float* __restrict__ y3, const float* __restrict__ scal,
                       float* __restrict__ genr) {
    __shared__ float tile[C3H * C3W];
    int m = blockIdx.x;
    float a = scal[6], b = scal[7];
    for (int i = threadIdx.x; i < C3H * C3W; i += blockDim.x) {
        float v = a * y3[m * C3H * C3W + i] + b;
        tile[i] = v >= 0.f ? v : 0.1f * v;
    }
    __syncthreads();
    const float cw0 = 4.f / 37.f, cw1 = 5.f / 37.f, cw2 = 6.f / 37.f, cw3 = 7.f / 37.f;
    const float cw[7] = { cw0, cw1, cw2, cw3, cw2, cw1, cw0 };
    for (int i = threadIdx.x; i < RHN; i += blockDim.x) {
        float sh = (i + 0.5f) * (113.0f / 1024.0f) - 0.5f;
        float fl = floorf(sh);
        float fr = sh - fl;
        int i0 = (int)fl, i1 = i0 + 1;
        i0 = max(0, min(C3H - 1, i0));
        i1 = max(0, min(C3H - 1, i1));
        float acc = 0.f;
#pragma unroll
        for (int x = 0; x < 7; x++) {
            float v = (1.f - fr) * tile[i0 * C3W + x] + fr * tile[i1 * C3W + x];
            acc += cw[x] * v;
        }
        genr[m * RHN + i] = acc;
    }
}

// ---- K11: mix = sum_k genr * resized_mask, mask resize fused on the fly ----
__global__ void k_mix(const float* __restrict__ genr, const int* __restrict__ vint,
                      float* __restrict__ mix) {
    int bh = blockIdx.x;
    int h = bh % RHN, b = bh / RHN;
    __shared__ float g[KG];
    __shared__ int v0[KG], v1[KG];
    float sh = (h + 0.5f) * 0.25f - 0.5f;
    float fl = floorf(sh);
    float fh = sh - fl;
    int ih0 = (int)fl, ih1 = ih0 + 1;
    ih0 = max(0, min(HH - 1, ih0));
    ih1 = max(0, min(HH - 1, ih1));
    if (threadIdx.x < KG) {
        int k = threadIdx.x;
        int m = b * KG + k;
        g[k]  = genr[m * RHN + h];
        v0[k] = vint[m * HH + ih0];
        v1[k] = vint[m * HH + ih1];
    }
    __syncthreads();
    float G = 0.f;
#pragma unroll
    for (int k = 0; k < KG; k++) G += g[k];
    for (int w = threadIdx.x; w < RWN; w += blockDim.x) {
        float sw = (w + 0.5f) * 0.5f - 0.5f;
        float flw = floorf(sw);
        float fw = sw - flw;
        int iw0 = (int)flw, iw1 = iw0 + 1;
        iw0 = max(0, min(WCN - 1, iw0));
        iw1 = max(0, min(WCN - 1, iw1));
        float S = 0.f;
#pragma unroll
        for (int k = 0; k < KG; k++) {
            float b0 = ((iw0 == v0[k]) ? (1.f - fw) : 0.f) + ((iw1 == v0[k]) ? fw : 0.f);
            float b1 = ((iw0 == v1[k]) ? (1.f - fw) : 0.f) + ((iw1 == v1[k]) ? fw : 0.f);
            S += g[k] * ((1.f - fh) * b0 + fh * b1);
        }
        mix[((size_t)b * RHN + h) * RWN + w] = 0.01f * G + 0.9f * S;
    }
}

// ---- K12: final conv 3x3 pad 1 over mix; BNf stats; writes raw conv to out ----
__global__ void k_convf(const float* __restrict__ mix, const float* __restrict__ wf,
                        const float* __restrict__ bf, float* __restrict__ out, double* sums) {
    double s = 0, ss = 0;
    float w[9];
#pragma unroll
    for (int i = 0; i < 9; i++) w[i] = wf[i];
    float bb = bf[0];
    int stride = gridDim.x * blockDim.x;
    for (int idx = blockIdx.x * blockDim.x + threadIdx.x; idx < NF; idx += stride) {
        int x  = idx % RWN;
        int t2 = idx / RWN;
        int y  = t2 % RHN;
        int b  = t2 / RHN;
        const float* p = mix + (size_t)b * RHN * RWN;
        float acc = bb;
#pragma unroll
        for (int r = 0; r < 3; r++) {
            int hh = y - 1 + r;
            if (hh < 0 || hh >= RHN) continue;
#pragma unroll
            for (int c = 0; c < 3; c++) {
                int ww = x - 1 + c;
                if (ww < 0 || ww >= RWN) continue;
                acc += w[r * 3 + c] * p[(size_t)hh * RWN + ww];
            }
        }
        out[idx] = acc;
        s += acc; ss += (double)acc * acc;
    }
    blockAdd2(s, ss, &sums[8 * SL], &sums[9 * SL]);
}

// ---- final affine + LReLU on out, float4 ----
__global__ void k_act4(float4* __restrict__ x, const float* __restrict__ ab, int n4) {
    int i = blockIdx.x * blockDim.x + threadIdx.x;
    if (i < n4) {
        float a = ab[0], b = ab[1];
        float4 v = x[i];
        v.x = a * v.x + b; v.x = v.x >= 0.f ? v.x : 0.1f * v.x;
        v.y = a * v.y + b; v.y = v.y >= 0.f ? v.y : 0.1f * v.y;
        v.z = a * v.z + b; v.z = v.z >= 0.f ? v.z : 0.1f * v.z;
        v.w = a * v.w + b; v.w = v.w >= 0.f ? v.w : 0.1f * v.w;
        x[i] = v;
    }
}

extern "C" void kernel_launch(void* const* d_in, const int* in_sizes, int n_in,
                              void* d_out, int out_size, void* d_ws, size_t ws_size,
                              hipStream_t stream) {
    const float* gather = (const float*)d_in[0];
    const float* cv     = (const float*)d_in[1];
    const float* VMM    = (const float*)d_in[2];
    const float* w1 = (const float*)d_in[3];
    const float* b1 = (const float*)d_in[4];
    const float* g1 = (const float*)d_in[5];
    const float* be1 = (const float*)d_in[6];
    const float* w2 = (const float*)d_in[7];
    const float* b2 = (const float*)d_in[8];
    const float* g2 = (const float*)d_in[9];
    const float* be2 = (const float*)d_in[10];
    const float* w3 = (const float*)d_in[11];
    const float* b3 = (const float*)d_in[12];
    const float* g3 = (const float*)d_in[13];
    const float* be3 = (const float*)d_in[14];
    const float* wf = (const float*)d_in[15];
    const float* bf = (const float*)d_in[16];
    const float* gf = (const float*)d_in[17];
    const float* bef = (const float*)d_in[18];
    float* out = (float*)d_out;

    char* ws = (char*)d_ws;
    double* sums        = (double*)ws;
    unsigned int* amax  = (unsigned int*)(ws + OFF_AMAX);
    float* scal         = (float*)(ws + OFF_SCAL);
    int*   vint         = (int*)(ws + OFF_VINT);
    float* y1           = (float*)(ws + OFF_Y1);
    float* mp3          = (float*)(ws + OFF_MP3);
    float* mp5          = (float*)(ws + OFF_MP5);
    float* y2           = (float*)(ws + OFF_Y2);
    float* y3           = (float*)(ws + OFF_Y3);
    float* genr         = (float*)(ws + OFF_GENR);
    float* mix          = (float*)(ws + OFF_MIX);
    float* act          = (float*)(ws + OFF_ACT);  // aliases mix

    hipMemsetAsync(d_ws, 0, 768, stream);

    k_absmax<<<512, 256, 0, stream>>>(gather, amax);
    k_conv1<<<512, 256, 0, stream>>>(gather, w1, b1, amax, y1, sums);
    k_bnfin<<<1, 64, 0, stream>>>(sums + 0, g1, be1, scal + 0, 1, (double)N1);
    k_actpools<<<(N1 + 255) / 256, 256, 0, stream>>>(y1, scal, act, mp3, mp5);
    k_conv2<<<512, 256, 0, stream>>>(act, mp3, mp5, w2, b2, y2, sums);
    k_bnfin<<<1, 64, 0, stream>>>(sums + 2 * SL, g2, be2, scal + 2, 2, (double)N2);
    k_conv3<<<198, 256, 0, stream>>>(y2, scal, w3, b3, y3, sums);
    k_bnfin<<<1, 64, 0, stream>>>(sums + 6 * SL, g3, be3, scal + 6, 1, (double)N3);
    k_vint<<<MM, 256, 0, stream>>>(cv, VMM, vint);
    k_genr<<<MM, 256, 0, stream>>>(y3, scal, genr);
    k_mix<<<BSZ * RHN, 256, 0, stream>>>(genr, vint, mix);
    k_convf<<<1024, 256, 0, stream>>>(mix, wf, bf, out, sums);
    k_bnfin<<<1, 64, 0, stream>>>(sums + 8 * SL, gf, bef, scal + 8, 1, (double)NF);
    k_act4<<<(NF / 4 + 255) / 256, 256, 0, stream>>>((float4*)out, scal + 8, NF / 4);
}

// Round 3
// 205.847 us; speedup vs baseline: 2.0931x; 1.3416x over previous
//
#include <hip/hip_runtime.h>
#include <math.h>

#define BSZ 8
#define KG  8
#define NP  16
#define MM  64            // BS*K
#define TT  3072
#define WGN 64
#define HH  256
#define WCN 256
#define RHN 1024
#define RWN 512

#define C1H 1024
#define C1W 31
#define C2H 341
#define C2W 15
#define C3H 113
#define C3W 7

#define N_GATHER (MM*TT*WGN)          // 12,582,912
#define N1 (MM*C1H*C1W)               // 2,031,616
#define N2 (MM*C2H*C2W)               // 327,360 (per channel)
#define N3 (MM*C3H*C3W)               // 50,624
#define NF (BSZ*RHN*RWN)              // 4,194,304

#define SL 8   // atomic spread slots

// ---- workspace byte offsets ----
// [0,640)   : double sums[10][SL]
// [640,672) : uint absmax[SL]
// [672,712) : float scal[10]
// [768,...) : vint, y1, y2, y3, genr
#define OFF_AMAX 640
#define OFF_SCAL 672
#define OFF_VINT 768
#define OFF_Y1   (OFF_VINT + MM*HH*4)
#define OFF_Y2   (OFF_Y1  + N1*4)
#define OFF_Y3   (OFF_Y2  + 2*N2*4)
#define OFF_GENR (OFF_Y3  + N3*4)

__device__ __forceinline__ void blockAdd2(double s, double ss, double* o0, double* o1) {
    __shared__ double red[4][2];
    __syncthreads();
    int lane = threadIdx.x & 63, wid = threadIdx.x >> 6;
#pragma unroll
    for (int off = 32; off > 0; off >>= 1) {
        s  += __shfl_down(s,  off, 64);
        ss += __shfl_down(ss, off, 64);
    }
    if (lane == 0) { red[wid][0] = s; red[wid][1] = ss; }
    __syncthreads();
    if (threadIdx.x == 0) {
        double a = 0, b = 0;
        int nw = blockDim.x >> 6;
        for (int i = 0; i < nw; i++) { a += red[i][0]; b += red[i][1]; }
        int slot = blockIdx.x & (SL - 1);
        atomicAdd(&o0[slot], a); atomicAdd(&o1[slot], b);
    }
}

// ---- K1: global absmax; 1 atomic per block, spread over SL slots ----
__global__ void k_absmax(const float* __restrict__ g, unsigned int* amax) {
    __shared__ float red[4];
    int tid = blockIdx.x * blockDim.x + threadIdx.x;
    int stride = gridDim.x * blockDim.x;
    const float4* g4 = (const float4*)g;
    float m = 0.f;
    for (int i = tid; i < N_GATHER / 4; i += stride) {
        float4 v = g4[i];
        m = fmaxf(m, fmaxf(fmaxf(fabsf(v.x), fabsf(v.y)), fmaxf(fabsf(v.z), fabsf(v.w))));
    }
#pragma unroll
    for (int off = 32; off > 0; off >>= 1) m = fmaxf(m, __shfl_down(m, off, 64));
    int lane = threadIdx.x & 63, wid = threadIdx.x >> 6;
    if (lane == 0) red[wid] = m;
    __syncthreads();
    if (threadIdx.x == 0) {
        float mm = fmaxf(fmaxf(red[0], red[1]), fmaxf(red[2], red[3]));
        atomicMax(&amax[blockIdx.x & (SL - 1)], __float_as_uint(mm));
    }
}

// ---- K2: conv1 (1x1x3x3, stride 3x2, VALID) with /absmax folded; BN1 stats ----
__global__ void k_conv1(const float* __restrict__ g, const float* __restrict__ w1,
                        const float* __restrict__ b1, const unsigned int* __restrict__ amax,
                        float* __restrict__ y1, double* sums) {
    float mx = 0.f;
#pragma unroll
    for (int i = 0; i < SL; i++) mx = fmaxf(mx, __uint_as_float(amax[i]));
    float inv = 1.0f / mx;
    float w[9];
#pragma unroll
    for (int i = 0; i < 9; i++) w[i] = w1[i] * inv;
    float bb = b1[0];
    double s = 0, ss = 0;
    int stride = gridDim.x * blockDim.x;
    for (int idx = blockIdx.x * blockDim.x + threadIdx.x; idx < N1; idx += stride) {
        int ow = idx % C1W;
        int t2 = idx / C1W;
        int oh = t2 % C1H;
        int m  = t2 / C1H;
        const float* xp = g + (size_t)m * TT * WGN + (size_t)(oh * 3) * WGN + ow * 2;
        float acc = bb;
#pragma unroll
        for (int r = 0; r < 3; r++)
#pragma unroll
            for (int c = 0; c < 3; c++) acc += w[r * 3 + c] * xp[r * WGN + c];
        y1[idx] = acc;
        s += acc; ss += (double)acc * (double)acc;
    }
    blockAdd2(s, ss, &sums[0], &sums[SL]);
}

// ---- BN finalize over SL slots ----
__global__ void k_bnfin(const double* __restrict__ s, const float* __restrict__ g,
                        const float* __restrict__ be, float* __restrict__ ab,
                        int nch, double n) {
    int c = threadIdx.x;
    if (c < nch) {
        double sum = 0, sumsq = 0;
        for (int j = 0; j < SL; j++) {
            sum   += s[(2 * c) * SL + j];
            sumsq += s[(2 * c + 1) * SL + j];
        }
        double mean = sum / n;
        double var  = sumsq / n - mean * mean;
        double a = (double)g[c] / sqrt(var + 1e-5);
        ab[2 * c]     = (float)a;
        ab[2 * c + 1] = (float)((double)be[c] - mean * a);
    }
}

// ---- K4: fused BN1-act + maxpool3/5 (separable, LDS) + conv2; BN2 stats ----
// block: (m, 32-output-row chunk of C2H=341). LDS: act/r3/r5 tiles 100x32.
#define F2_OH 32
#define F2_NCH 11                    // ceil(341/32)
#define F2_NRMAX (3*F2_OH + 4)       // 100
__global__ void k_fused2(const float* __restrict__ y1, const float* __restrict__ scal,
                         const float* __restrict__ w2, const float* __restrict__ b2,
                         float* __restrict__ y2, double* sums) {
    __shared__ float sact[F2_NRMAX][32];
    __shared__ float sr3[F2_NRMAX][32];
    __shared__ float sr5[F2_NRMAX][32];
    int m   = blockIdx.x / F2_NCH;
    int ch  = blockIdx.x % F2_NCH;
    int oh0 = ch * F2_OH;
    int OHa = min(F2_OH, C2H - oh0);
    int NR  = 3 * OHa + 4;
    int gl0 = 3 * oh0 - 2;
    float a1 = scal[0], b1 = scal[1];
    const float* yp = y1 + (size_t)m * C1H * C1W;
    // phase A: activated conv1 output into LDS (-inf for out-of-range rows)
    for (int i = threadIdx.x; i < NR * C1W; i += blockDim.x) {
        int l = i / C1W, w = i % C1W;
        int gr = gl0 + l;
        float v = -INFINITY;
        if (gr >= 0 && gr < C1H) {
            v = a1 * yp[gr * C1W + w] + b1;
            v = v >= 0.f ? v : 0.1f * v;
        }
        sact[l][w] = v;
    }
    __syncthreads();
    // phase B: horizontal running max-3 / max-5 (cols clamp == -inf pad)
    for (int i = threadIdx.x; i < NR * C1W; i += blockDim.x) {
        int l = i / C1W, w = i % C1W;
        int wl1 = max(w - 1, 0), wr1 = min(w + 1, C1W - 1);
        int wl2 = max(w - 2, 0), wr2 = min(w + 2, C1W - 1);
        float c  = sact[l][w];
        float m3 = fmaxf(fmaxf(sact[l][wl1], c), sact[l][wr1]);
        float m5 = fmaxf(fmaxf(m3, sact[l][wl2]), sact[l][wr2]);
        sr3[l][w] = m3;
        sr5[l][w] = m5;
    }
    __syncthreads();
    // phase C: conv2 (2 out ch, 3 in ch where ch1/ch2 = vertical max of r3/r5)
    double s0 = 0, ss0 = 0, s1 = 0, ss1 = 0;
    for (int o = threadIdx.x; o < OHa * C2W; o += blockDim.x) {
        int lo = o / C2W, ow = o % C2W;
        float a0 = b2[0], acc1 = b2[1];
#pragma unroll
        for (int i = 0; i < 3; i++) {
            int l = 3 * lo + 2 + i;
#pragma unroll
            for (int j = 0; j < 3; j++) {
                int wc = 2 * ow + j;
                float v0 = sact[l][wc];
                float v1 = fmaxf(fmaxf(sr3[l - 1][wc], sr3[l][wc]), sr3[l + 1][wc]);
                float v2 = fmaxf(fmaxf(fmaxf(sr5[l - 2][wc], sr5[l - 1][wc]), sr5[l][wc]),
                                 fmaxf(sr5[l + 1][wc], sr5[l + 2][wc]));
                int ki = i * 3 + j;
                a0   += w2[ki] * v0 + w2[9 + ki] * v1 + w2[18 + ki] * v2;
                acc1 += w2[27 + ki] * v0 + w2[36 + ki] * v1 + w2[45 + ki] * v2;
            }
        }
        size_t ob = (size_t)m * (2 * C2H * C2W) + (size_t)(oh0 + lo) * C2W + ow;
        y2[ob] = a0;
        y2[ob + C2H * C2W] = acc1;
        s0 += a0; ss0 += (double)a0 * a0;
        s1 += acc1; ss1 += (double)acc1 * acc1;
    }
    blockAdd2(s0, ss0, &sums[2 * SL], &sums[3 * SL]);
    blockAdd2(s1, ss1, &sums[4 * SL], &sums[5 * SL]);
}

// ---- K6: conv3 (1x2x3x2, stride 3x2), BN2 act on the fly; BN3 stats ----
__global__ void k_conv3(const float* __restrict__ y2, const float* __restrict__ scal,
                        const float* __restrict__ w3, const float* __restrict__ b3,
                        float* __restrict__ y3, double* sums) {
    double s = 0, ss = 0;
    float a20 = scal[2], b20 = scal[3], a21 = scal[4], b21 = scal[5];
    int stride = gridDim.x * blockDim.x;
    for (int idx = blockIdx.x * blockDim.x + threadIdx.x; idx < N3; idx += stride) {
        int ow = idx % C3W;
        int t2 = idx / C3W;
        int oh = t2 % C3H;
        int m  = t2 / C3H;
        float acc = b3[0];
#pragma unroll
        for (int i = 0; i < 2; i++) {
            float aa = i ? a21 : a20, bb = i ? b21 : b20;
            const float* cp = y2 + (size_t)m * (2 * C2H * C2W) + (size_t)i * C2H * C2W
                              + (size_t)(oh * 3) * C2W + ow * 2;
#pragma unroll
            for (int r = 0; r < 3; r++)
#pragma unroll
                for (int c = 0; c < 2; c++) {
                    float v = aa * cp[r * C2W + c] + bb;
                    v = v >= 0.f ? v : 0.1f * v;
                    acc += w3[i * 6 + r * 2 + c] * v;
                }
        }
        y3[idx] = acc;
        s += acc; ss += (double)acc * acc;
    }
    blockAdd2(s, ss, &sums[6 * SL], &sums[7 * SL]);
}

// ---- K8: per-curve interp -> v_int[m][h] ----
__global__ void k_vint(const float* __restrict__ cv, const float* __restrict__ VMM,
                       int* __restrict__ vint) {
    __shared__ float tt[NP], vv[NP];
    int m = blockIdx.x;
    int b = m >> 3;
    if (threadIdx.x < NP) {
        int n = threadIdx.x;
        float t = cv[(m * NP + n) * 2 + 0];
        float v = cv[(m * NP + n) * 2 + 1];
        float dt = 7000.0f / 255.0f;
        tt[n] = t / dt;
        float vmin = VMM[b * 2], vmax = VMM[b * 2 + 1];
        float dv = (vmax - vmin) / 255.0f;
        vv[n] = (v - vmin) / dv;
    }
    __syncthreads();
    int h = threadIdx.x;
    float x = (float)h;
    float val;
    if (x <= tt[0]) val = vv[0];
    else if (x >= tt[NP - 1]) val = vv[NP - 1];
    else {
        int i = 1;
        while (i < NP - 1 && tt[i] <= x) i++;
        float d = tt[i] - tt[i - 1];
        val = (d != 0.f) ? vv[i - 1] + (x - tt[i - 1]) / d * (vv[i] - vv[i - 1]) : vv[i];
    }
    int vi = (int)val;
    vi = max(0, min(WCN - 1, vi));
    vint[m * HH + h] = vi;
}

// ---- K9: BN3 act + resize (113,7)->(1024,1) ----
__global__ void k_genr(const float* __restrict__ y3, const float* __restrict__ scal,
                       float* __restrict__ genr) {
    __shared__ float tile[C3H * C3W];
    int m = blockIdx.x;
    float a = scal[6], b = scal[7];
    for (int i = threadIdx.x; i < C3H * C3W; i += blockDim.x) {
        float v = a * y3[m * C3H * C3W + i] + b;
        tile[i] = v >= 0.f ? v : 0.1f * v;
    }
    __syncthreads();
    const float cw0 = 4.f / 37.f, cw1 = 5.f / 37.f, cw2 = 6.f / 37.f, cw3 = 7.f / 37.f;
    const float cw[7] = { cw0, cw1, cw2, cw3, cw2, cw1, cw0 };
    for (int i = threadIdx.x; i < RHN; i += blockDim.x) {
        float sh = (i + 0.5f) * (113.0f / 1024.0f) - 0.5f;
        float fl = floorf(sh);
        float fr = sh - fl;
        int i0 = (int)fl, i1 = i0 + 1;
        i0 = max(0, min(C3H - 1, i0));
        i1 = max(0, min(C3H - 1, i1));
        float acc = 0.f;
#pragma unroll
        for (int x = 0; x < 7; x++) {
            float v = (1.f - fr) * tile[i0 * C3W + x] + fr * tile[i1 * C3W + x];
            acc += cw[x] * v;
        }
        genr[m * RHN + i] = acc;
    }
}

// ---- K10: fused mix + final 3x3 conv; BNf stats. mix tile built in LDS by
// column-scatter (x2 upsample: src col v -> out cols 2v-1..2v+2, w {.25,.75,.75,.25},
// edges v=0 -> col0 w=1, v=255 -> col511 w=1). Rows outside [0,1023] stay zero. ----
#define MC_TH 16
__global__ void k_mixconvf(const float* __restrict__ genr, const int* __restrict__ vint,
                           const float* __restrict__ wf, const float* __restrict__ bf,
                           float* __restrict__ out, double* sums) {
    __shared__ float tile[MC_TH + 2][RWN + 2];
    __shared__ float Grow[MC_TH + 2];
    int b  = blockIdx.x / (RHN / MC_TH);
    int chk = blockIdx.x % (RHN / MC_TH);
    int h0 = chk * MC_TH;
    // zero init
    for (int i = threadIdx.x; i < (MC_TH + 2) * (RWN + 2); i += blockDim.x)
        ((float*)tile)[i] = 0.f;
    if (threadIdx.x < MC_TH + 2) Grow[threadIdx.x] = 0.f;
    __syncthreads();
    // phase 1: scatter mask contributions; one thread per (row, k)
    if (threadIdx.x < (MC_TH + 2) * KG) {
        int r = threadIdx.x / KG, k = threadIdx.x % KG;
        int h = h0 - 1 + r;
        if (h >= 0 && h < RHN) {
            int m = b * KG + k;
            float g = genr[m * RHN + h];
            atomicAdd(&Grow[r], g);
            float sh = (h + 0.5f) * 0.25f - 0.5f;
            float fl = floorf(sh);
            float fh = sh - fl;
            int ih0 = (int)fl, ih1 = ih0 + 1;
            ih0 = max(0, min(HH - 1, ih0));
            ih1 = max(0, min(HH - 1, ih1));
            int vv[2] = { vint[m * HH + ih0], vint[m * HH + ih1] };
            float aa[2] = { 0.9f * g * (1.f - fh), 0.9f * g * fh };
#pragma unroll
            for (int t = 0; t < 2; t++) {
                int v = vv[t]; float A = aa[t];
                if (v == 0) {
                    atomicAdd(&tile[r][1 + 0], A);
                    atomicAdd(&tile[r][1 + 1], 0.75f * A);
                    atomicAdd(&tile[r][1 + 2], 0.25f * A);
                } else if (v == WCN - 1) {
                    atomicAdd(&tile[r][1 + 509], 0.25f * A);
                    atomicAdd(&tile[r][1 + 510], 0.75f * A);
                    atomicAdd(&tile[r][1 + 511], A);
                } else {
                    atomicAdd(&tile[r][1 + 2 * v - 1], 0.25f * A);
                    atomicAdd(&tile[r][1 + 2 * v],     0.75f * A);
                    atomicAdd(&tile[r][1 + 2 * v + 1], 0.75f * A);
                    atomicAdd(&tile[r][1 + 2 * v + 2], 0.25f * A);
                }
            }
        }
    }
    __syncthreads();
    // phase 1b: add the 0.01*G background (invalid rows have Grow=0, stay 0)
    for (int i = threadIdx.x; i < (MC_TH + 2) * RWN; i += blockDim.x) {
        int r = i / RWN, w = i % RWN;
        int h = h0 - 1 + r;
        if (h >= 0 && h < RHN) tile[r][w + 1] += 0.01f * Grow[r];
    }
    __syncthreads();
    // phase 2: 3x3 conv from LDS, write raw conv + stats
    float w[9];
#pragma unroll
    for (int i = 0; i < 9; i++) w[i] = wf[i];
    float bb = bf[0];
    double s = 0, ss = 0;
    for (int o = threadIdx.x; o < MC_TH * RWN; o += blockDim.x) {
        int lr = o / RWN, x = o % RWN;
        float acc = bb;
#pragma unroll
        for (int dr = 0; dr < 3; dr++)
#pragma unroll
            for (int dc = 0; dc < 3; dc++)
                acc += w[dr * 3 + dc] * tile[lr + dr][x + dc];
        out[((size_t)b * RHN + (h0 + lr)) * RWN + x] = acc;
        s += acc; ss += (double)acc * acc;
    }
    blockAdd2(s, ss, &sums[8 * SL], &sums[9 * SL]);
}

// ---- final affine + LReLU on out, float4 ----
__global__ void k_act4(float4* __restrict__ x, const float* __restrict__ ab, int n4) {
    int i = blockIdx.x * blockDim.x + threadIdx.x;
    if (i < n4) {
        float a = ab[0], b = ab[1];
        float4 v = x[i];
        v.x = a * v.x + b; v.x = v.x >= 0.f ? v.x : 0.1f * v.x;
        v.y = a * v.y + b; v.y = v.y >= 0.f ? v.y : 0.1f * v.y;
        v.z = a * v.z + b; v.z = v.z >= 0.f ? v.z : 0.1f * v.z;
        v.w = a * v.w + b; v.w = v.w >= 0.f ? v.w : 0.1f * v.w;
        x[i] = v;
    }
}

extern "C" void kernel_launch(void* const* d_in, const int* in_sizes, int n_in,
                              void* d_out, int out_size, void* d_ws, size_t ws_size,
                              hipStream_t stream) {
    const float* gather = (const float*)d_in[0];
    const float* cv     = (const float*)d_in[1];
    const float* VMM    = (const float*)d_in[2];
    const float* w1 = (const float*)d_in[3];
    const float* b1 = (const float*)d_in[4];
    const float* g1 = (const float*)d_in[5];
    const float* be1 = (const float*)d_in[6];
    const float* w2 = (const float*)d_in[7];
    const float* b2 = (const float*)d_in[8];
    const float* g2 = (const float*)d_in[9];
    const float* be2 = (const float*)d_in[10];
    const float* w3 = (const float*)d_in[11];
    const float* b3 = (const float*)d_in[12];
    const float* g3 = (const float*)d_in[13];
    const float* be3 = (const float*)d_in[14];
    const float* wf = (const float*)d_in[15];
    const float* bf = (const float*)d_in[16];
    const float* gf = (const float*)d_in[17];
    const float* bef = (const float*)d_in[18];
    float* out = (float*)d_out;

    char* ws = (char*)d_ws;
    double* sums        = (double*)ws;
    unsigned int* amax  = (unsigned int*)(ws + OFF_AMAX);
    float* scal         = (float*)(ws + OFF_SCAL);
    int*   vint         = (int*)(ws + OFF_VINT);
    float* y1           = (float*)(ws + OFF_Y1);
    float* y2           = (float*)(ws + OFF_Y2);
    float* y3           = (float*)(ws + OFF_Y3);
    float* genr         = (float*)(ws + OFF_GENR);

    hipMemsetAsync(d_ws, 0, 768, stream);

    k_absmax<<<512, 256, 0, stream>>>(gather, amax);
    k_conv1<<<512, 256, 0, stream>>>(gather, w1, b1, amax, y1, sums);
    k_bnfin<<<1, 64, 0, stream>>>(sums + 0, g1, be1, scal + 0, 1, (double)N1);
    k_fused2<<<MM * F2_NCH, 256, 0, stream>>>(y1, scal, w2, b2, y2, sums);
    k_bnfin<<<1, 64, 0, stream>>>(sums + 2 * SL, g2, be2, scal + 2, 2, (double)N2);
    k_conv3<<<198, 256, 0, stream>>>(y2, scal, w3, b3, y3, sums);
    k_bnfin<<<1, 64, 0, stream>>>(sums + 6 * SL, g3, be3, scal + 6, 1, (double)N3);
    k_vint<<<MM, 256, 0, stream>>>(cv, VMM, vint);
    k_genr<<<MM, 256, 0, stream>>>(y3, scal, genr);
    k_mixconvf<<<BSZ * (RHN / MC_TH), 256, 0, stream>>>(genr, vint, wf, bf, out, sums);
    k_bnfin<<<1, 64, 0, stream>>>(sums + 8 * SL, gf, bef, scal + 8, 1, (double)NF);
    k_act4<<<(NF / 4 + 255) / 256, 256, 0, stream>>>((float4*)out, scal + 8, NF / 4);
}

// Round 4
// 196.937 us; speedup vs baseline: 2.1878x; 1.0452x over previous
//
#include <hip/hip_runtime.h>
#include <math.h>

#define BSZ 8
#define KG  8
#define NP  16
#define MM  64            // BS*K
#define TT  3072
#define WGN 64
#define HH  256
#define WCN 256
#define RHN 1024
#define RWN 512

#define C1H 1024
#define C1W 31
#define C2H 341
#define C2W 15
#define C3H 113
#define C3W 7

#define N1 (MM*C1H*C1W)               // 2,031,616
#define N2 (MM*C2H*C2W)               // 327,360 (per channel)
#define N3 (MM*C3H*C3W)               // 50,624
#define NF (BSZ*RHN*RWN)              // 4,194,304

#define SL 8   // atomic spread slots

// ---- workspace byte offsets ----
// [0,640)   : double sums[10][SL]  {s1,ss1, s2c0,ss2c0, s2c1,ss2c1, s3,ss3, sf,ssf}
// [768,...) : vint, y1, y2, y3, genr
#define OFF_VINT 768
#define OFF_Y1   (OFF_VINT + MM*HH*4)
#define OFF_Y2   (OFF_Y1  + N1*4)
#define OFF_Y3   (OFF_Y2  + 2*N2*4)
#define OFF_GENR (OFF_Y3  + N3*4)

__device__ __forceinline__ void blockAdd2(double s, double ss, double* o0, double* o1) {
    __shared__ double red[4][2];
    __syncthreads();
    int lane = threadIdx.x & 63, wid = threadIdx.x >> 6;
#pragma unroll
    for (int off = 32; off > 0; off >>= 1) {
        s  += __shfl_down(s,  off, 64);
        ss += __shfl_down(ss, off, 64);
    }
    if (lane == 0) { red[wid][0] = s; red[wid][1] = ss; }
    __syncthreads();
    if (threadIdx.x == 0) {
        double a = 0, b = 0;
        int nw = blockDim.x >> 6;
        for (int i = 0; i < nw; i++) { a += red[i][0]; b += red[i][1]; }
        int slot = blockIdx.x & (SL - 1);
        atomicAdd(&o0[slot], a); atomicAdd(&o1[slot], b);
    }
}

// BN fold computed inline by consumers: a = g/sqrt(var+eps), b = be - mean*a
__device__ __forceinline__ float2 bn_ab(const double* __restrict__ sums, int c,
                                        const float* __restrict__ g,
                                        const float* __restrict__ be, double n) {
    double sum = 0, sumsq = 0;
#pragma unroll
    for (int j = 0; j < SL; j++) {
        sum   += sums[(2 * c) * SL + j];
        sumsq += sums[(2 * c + 1) * SL + j];
    }
    double mean = sum / n;
    double var  = sumsq / n - mean * mean;
    double a = (double)g[c] / sqrt(var + 1e-5);
    return make_float2((float)a, (float)((double)be[c] - mean * a));
}

// ---- K1: conv1 (1x1x3x3, stride 3x2, VALID). NOTE: the reference's x/absmax(x)
// normalization and b1 are dropped — both are uniform affine transforms of the
// conv output, removed exactly by the training-mode BN that follows (LReLU and
// maxpool are positive-homogeneous, so downstream BNs absorb the eps residual).
__global__ void k_conv1(const float* __restrict__ g, const float* __restrict__ w1,
                        const float* __restrict__ b1,
                        float* __restrict__ y1, double* sums) {
    float w[9];
#pragma unroll
    for (int i = 0; i < 9; i++) w[i] = w1[i];
    float bb = b1[0];
    double s = 0, ss = 0;
    int stride = gridDim.x * blockDim.x;
    for (int idx = blockIdx.x * blockDim.x + threadIdx.x; idx < N1; idx += stride) {
        int ow = idx % C1W;
        int t2 = idx / C1W;
        int oh = t2 % C1H;
        int m  = t2 / C1H;
        const float* xp = g + (size_t)m * TT * WGN + (size_t)(oh * 3) * WGN + ow * 2;
        float acc = bb;
#pragma unroll
        for (int r = 0; r < 3; r++)
#pragma unroll
            for (int c = 0; c < 3; c++) acc += w[r * 3 + c] * xp[r * WGN + c];
        y1[idx] = acc;
        s += acc; ss += (double)acc * (double)acc;
    }
    blockAdd2(s, ss, &sums[0], &sums[SL]);
}

// ---- K2: fused BN1-act + maxpool3/5 (separable, LDS) + conv2; BN2 stats ----
#define F2_OH 32
#define F2_NCH 11                    // ceil(341/32)
#define F2_NRMAX (3*F2_OH + 4)       // 100
__global__ void k_fused2(const float* __restrict__ y1, const double* __restrict__ sums_r,
                         const float* __restrict__ g1, const float* __restrict__ be1,
                         const float* __restrict__ w2, const float* __restrict__ b2,
                         float* __restrict__ y2, double* sums) {
    __shared__ float sact[F2_NRMAX][32];
    __shared__ float sr3[F2_NRMAX][32];
    __shared__ float sr5[F2_NRMAX][32];
    float2 ab1 = bn_ab(sums_r, 0, g1, be1, (double)N1);
    int m   = blockIdx.x / F2_NCH;
    int ch  = blockIdx.x % F2_NCH;
    int oh0 = ch * F2_OH;
    int OHa = min(F2_OH, C2H - oh0);
    int NR  = 3 * OHa + 4;
    int gl0 = 3 * oh0 - 2;
    const float* yp = y1 + (size_t)m * C1H * C1W;
    for (int i = threadIdx.x; i < NR * C1W; i += blockDim.x) {
        int l = i / C1W, w = i % C1W;
        int gr = gl0 + l;
        float v = -INFINITY;
        if (gr >= 0 && gr < C1H) {
            v = ab1.x * yp[gr * C1W + w] + ab1.y;
            v = v >= 0.f ? v : 0.1f * v;
        }
        sact[l][w] = v;
    }
    __syncthreads();
    for (int i = threadIdx.x; i < NR * C1W; i += blockDim.x) {
        int l = i / C1W, w = i % C1W;
        int wl1 = max(w - 1, 0), wr1 = min(w + 1, C1W - 1);
        int wl2 = max(w - 2, 0), wr2 = min(w + 2, C1W - 1);
        float c  = sact[l][w];
        float m3 = fmaxf(fmaxf(sact[l][wl1], c), sact[l][wr1]);
        float m5 = fmaxf(fmaxf(m3, sact[l][wl2]), sact[l][wr2]);
        sr3[l][w] = m3;
        sr5[l][w] = m5;
    }
    __syncthreads();
    double s0 = 0, ss0 = 0, s1 = 0, ss1 = 0;
    for (int o = threadIdx.x; o < OHa * C2W; o += blockDim.x) {
        int lo = o / C2W, ow = o % C2W;
        float a0 = b2[0], acc1 = b2[1];
#pragma unroll
        for (int i = 0; i < 3; i++) {
            int l = 3 * lo + 2 + i;
#pragma unroll
            for (int j = 0; j < 3; j++) {
                int wc = 2 * ow + j;
                float v0 = sact[l][wc];
                float v1 = fmaxf(fmaxf(sr3[l - 1][wc], sr3[l][wc]), sr3[l + 1][wc]);
                float v2 = fmaxf(fmaxf(fmaxf(sr5[l - 2][wc], sr5[l - 1][wc]), sr5[l][wc]),
                                 fmaxf(sr5[l + 1][wc], sr5[l + 2][wc]));
                int ki = i * 3 + j;
                a0   += w2[ki] * v0 + w2[9 + ki] * v1 + w2[18 + ki] * v2;
                acc1 += w2[27 + ki] * v0 + w2[36 + ki] * v1 + w2[45 + ki] * v2;
            }
        }
        size_t ob = (size_t)m * (2 * C2H * C2W) + (size_t)(oh0 + lo) * C2W + ow;
        y2[ob] = a0;
        y2[ob + C2H * C2W] = acc1;
        s0 += a0; ss0 += (double)a0 * a0;
        s1 += acc1; ss1 += (double)acc1 * acc1;
    }
    blockAdd2(s0, ss0, &sums[2 * SL], &sums[3 * SL]);
    blockAdd2(s1, ss1, &sums[4 * SL], &sums[5 * SL]);
}

// ---- K3: conv3 (1x2x3x2, stride 3x2), BN2 act inline; BN3 stats ----
__global__ void k_conv3(const float* __restrict__ y2, const double* __restrict__ sums_r,
                        const float* __restrict__ g2, const float* __restrict__ be2,
                        const float* __restrict__ w3, const float* __restrict__ b3,
                        float* __restrict__ y3, double* sums) {
    float2 ab20 = bn_ab(sums_r + 2 * SL, 0, g2, be2, (double)N2);
    float2 ab21 = bn_ab(sums_r + 2 * SL, 1, g2, be2, (double)N2);
    double s = 0, ss = 0;
    int stride = gridDim.x * blockDim.x;
    for (int idx = blockIdx.x * blockDim.x + threadIdx.x; idx < N3; idx += stride) {
        int ow = idx % C3W;
        int t2 = idx / C3W;
        int oh = t2 % C3H;
        int m  = t2 / C3H;
        float acc = b3[0];
#pragma unroll
        for (int i = 0; i < 2; i++) {
            float aa = i ? ab21.x : ab20.x, bb = i ? ab21.y : ab20.y;
            const float* cp = y2 + (size_t)m * (2 * C2H * C2W) + (size_t)i * C2H * C2W
                              + (size_t)(oh * 3) * C2W + ow * 2;
#pragma unroll
            for (int r = 0; r < 3; r++)
#pragma unroll
                for (int c = 0; c < 2; c++) {
                    float v = aa * cp[r * C2W + c] + bb;
                    v = v >= 0.f ? v : 0.1f * v;
                    acc += w3[i * 6 + r * 2 + c] * v;
                }
        }
        y3[idx] = acc;
        s += acc; ss += (double)acc * acc;
    }
    blockAdd2(s, ss, &sums[6 * SL], &sums[7 * SL]);
}

// ---- K4: per-curve interp -> vint; BN3 act + resize (113,7)->(1024,1) -> genr ----
__global__ void k_vintgenr(const float* __restrict__ cv, const float* __restrict__ VMM,
                           const float* __restrict__ y3, const double* __restrict__ sums_r,
                           const float* __restrict__ g3, const float* __restrict__ be3,
                           int* __restrict__ vint, float* __restrict__ genr) {
    __shared__ float tt[NP], vv[NP];
    __shared__ float tile[C3H * C3W];
    int m = blockIdx.x;
    int b = m >> 3;
    float2 ab3 = bn_ab(sums_r + 6 * SL, 0, g3, be3, (double)N3);
    if (threadIdx.x < NP) {
        int n = threadIdx.x;
        float t = cv[(m * NP + n) * 2 + 0];
        float v = cv[(m * NP + n) * 2 + 1];
        float dt = 7000.0f / 255.0f;
        tt[n] = t / dt;
        float vmin = VMM[b * 2], vmax = VMM[b * 2 + 1];
        float dv = (vmax - vmin) / 255.0f;
        vv[n] = (v - vmin) / dv;
    }
    for (int i = threadIdx.x; i < C3H * C3W; i += blockDim.x) {
        float v = ab3.x * y3[m * C3H * C3W + i] + ab3.y;
        tile[i] = v >= 0.f ? v : 0.1f * v;
    }
    __syncthreads();
    {   // vint: one thread per h
        int h = threadIdx.x;
        float x = (float)h;
        float val;
        if (x <= tt[0]) val = vv[0];
        else if (x >= tt[NP - 1]) val = vv[NP - 1];
        else {
            int i = 1;
            while (i < NP - 1 && tt[i] <= x) i++;
            float d = tt[i] - tt[i - 1];
            val = (d != 0.f) ? vv[i - 1] + (x - tt[i - 1]) / d * (vv[i] - vv[i - 1]) : vv[i];
        }
        int vi = (int)val;
        vint[m * HH + h] = max(0, min(WCN - 1, vi));
    }
    const float cw0 = 4.f / 37.f, cw1 = 5.f / 37.f, cw2 = 6.f / 37.f, cw3 = 7.f / 37.f;
    const float cw[7] = { cw0, cw1, cw2, cw3, cw2, cw1, cw0 };
    for (int i = threadIdx.x; i < RHN; i += blockDim.x) {
        float sh = (i + 0.5f) * (113.0f / 1024.0f) - 0.5f;
        float fl = floorf(sh);
        float fr = sh - fl;
        int i0 = (int)fl, i1 = i0 + 1;
        i0 = max(0, min(C3H - 1, i0));
        i1 = max(0, min(C3H - 1, i1));
        float acc = 0.f;
#pragma unroll
        for (int x = 0; x < 7; x++) {
            float v = (1.f - fr) * tile[i0 * C3W + x] + fr * tile[i1 * C3W + x];
            acc += cw[x] * v;
        }
        genr[m * RHN + i] = acc;
    }
}

// ---- shared tile builder for the fused mix+convf kernels ----
#define MC_TH 16
__device__ __forceinline__ void build_mix_tile(const float* __restrict__ genr,
                                               const int* __restrict__ vint,
                                               int b, int h0,
                                               float (*tile)[RWN + 2], float* Grow) {
    for (int i = threadIdx.x; i < (MC_TH + 2) * (RWN + 2); i += blockDim.x)
        ((float*)tile)[i] = 0.f;
    if (threadIdx.x < MC_TH + 2) Grow[threadIdx.x] = 0.f;
    __syncthreads();
    if (threadIdx.x < (MC_TH + 2) * KG) {
        int r = threadIdx.x / KG, k = threadIdx.x % KG;
        int h = h0 - 1 + r;
        if (h >= 0 && h < RHN) {
            int m = b * KG + k;
            float g = genr[m * RHN + h];
            atomicAdd(&Grow[r], g);
            float sh = (h + 0.5f) * 0.25f - 0.5f;
            float fl = floorf(sh);
            float fh = sh - fl;
            int ih0 = (int)fl, ih1 = ih0 + 1;
            ih0 = max(0, min(HH - 1, ih0));
            ih1 = max(0, min(HH - 1, ih1));
            int vv[2] = { vint[m * HH + ih0], vint[m * HH + ih1] };
            float aa[2] = { 0.9f * g * (1.f - fh), 0.9f * g * fh };
#pragma unroll
            for (int t = 0; t < 2; t++) {
                int v = vv[t]; float A = aa[t];
                if (v == 0) {
                    atomicAdd(&tile[r][1 + 0], A);
                    atomicAdd(&tile[r][1 + 1], 0.75f * A);
                    atomicAdd(&tile[r][1 + 2], 0.25f * A);
                } else if (v == WCN - 1) {
                    atomicAdd(&tile[r][1 + 509], 0.25f * A);
                    atomicAdd(&tile[r][1 + 510], 0.75f * A);
                    atomicAdd(&tile[r][1 + 511], A);
                } else {
                    atomicAdd(&tile[r][1 + 2 * v - 1], 0.25f * A);
                    atomicAdd(&tile[r][1 + 2 * v],     0.75f * A);
                    atomicAdd(&tile[r][1 + 2 * v + 1], 0.75f * A);
                    atomicAdd(&tile[r][1 + 2 * v + 2], 0.25f * A);
                }
            }
        }
    }
    __syncthreads();
    for (int i = threadIdx.x; i < (MC_TH + 2) * RWN; i += blockDim.x) {
        int r = i / RWN, w = i % RWN;
        int h = h0 - 1 + r;
        if (h >= 0 && h < RHN) tile[r][w + 1] += 0.01f * Grow[r];
    }
    __syncthreads();
}

// ---- K5a: mix+convf stats-only pass ----
__global__ void k_mixA(const float* __restrict__ genr, const int* __restrict__ vint,
                       const float* __restrict__ wf, const float* __restrict__ bf,
                       double* sums) {
    __shared__ float tile[MC_TH + 2][RWN + 2];
    __shared__ float Grow[MC_TH + 2];
    int b   = blockIdx.x / (RHN / MC_TH);
    int h0  = (blockIdx.x % (RHN / MC_TH)) * MC_TH;
    build_mix_tile(genr, vint, b, h0, tile, Grow);
    float w[9];
#pragma unroll
    for (int i = 0; i < 9; i++) w[i] = wf[i];
    float bb = bf[0];
    double s = 0, ss = 0;
    for (int o = threadIdx.x; o < MC_TH * RWN; o += blockDim.x) {
        int lr = o / RWN, x = o % RWN;
        float acc = bb;
#pragma unroll
        for (int dr = 0; dr < 3; dr++)
#pragma unroll
            for (int dc = 0; dc < 3; dc++)
                acc += w[dr * 3 + dc] * tile[lr + dr][x + dc];
        s += acc; ss += (double)acc * acc;
    }
    blockAdd2(s, ss, &sums[8 * SL], &sums[9 * SL]);
}

// ---- K5b: mix+convf recompute + BNf affine + LReLU -> out (single write) ----
__global__ void k_mixB(const float* __restrict__ genr, const int* __restrict__ vint,
                       const float* __restrict__ wf, const float* __restrict__ bf,
                       const double* __restrict__ sums_r, const float* __restrict__ gf,
                       const float* __restrict__ bef, float* __restrict__ out) {
    __shared__ float tile[MC_TH + 2][RWN + 2];
    __shared__ float Grow[MC_TH + 2];
    float2 abf = bn_ab(sums_r + 8 * SL, 0, gf, bef, (double)NF);
    int b   = blockIdx.x / (RHN / MC_TH);
    int h0  = (blockIdx.x % (RHN / MC_TH)) * MC_TH;
    build_mix_tile(genr, vint, b, h0, tile, Grow);
    float w[9];
#pragma unroll
    for (int i = 0; i < 9; i++) w[i] = wf[i];
    float bb = bf[0];
    for (int o = threadIdx.x; o < MC_TH * RWN; o += blockDim.x) {
        int lr = o / RWN, x = o % RWN;
        float acc = bb;
#pragma unroll
        for (int dr = 0; dr < 3; dr++)
#pragma unroll
            for (int dc = 0; dc < 3; dc++)
                acc += w[dr * 3 + dc] * tile[lr + dr][x + dc];
        float v = abf.x * acc + abf.y;
        out[((size_t)b * RHN + (h0 + lr)) * RWN + x] = v >= 0.f ? v : 0.1f * v;
    }
}

extern "C" void kernel_launch(void* const* d_in, const int* in_sizes, int n_in,
                              void* d_out, int out_size, void* d_ws, size_t ws_size,
                              hipStream_t stream) {
    const float* gather = (const float*)d_in[0];
    const float* cv     = (const float*)d_in[1];
    const float* VMM    = (const float*)d_in[2];
    const float* w1 = (const float*)d_in[3];
    const float* b1 = (const float*)d_in[4];
    const float* g1 = (const float*)d_in[5];
    const float* be1 = (const float*)d_in[6];
    const float* w2 = (const float*)d_in[7];
    const float* b2 = (const float*)d_in[8];
    const float* g2 = (const float*)d_in[9];
    const float* be2 = (const float*)d_in[10];
    const float* w3 = (const float*)d_in[11];
    const float* b3 = (const float*)d_in[12];
    const float* g3 = (const float*)d_in[13];
    const float* be3 = (const float*)d_in[14];
    const float* wf = (const float*)d_in[15];
    const float* bf = (const float*)d_in[16];
    const float* gf = (const float*)d_in[17];
    const float* bef = (const float*)d_in[18];
    float* out = (float*)d_out;

    char* ws = (char*)d_ws;
    double* sums = (double*)ws;
    int*   vint  = (int*)(ws + OFF_VINT);
    float* y1    = (float*)(ws + OFF_Y1);
    float* y2    = (float*)(ws + OFF_Y2);
    float* y3    = (float*)(ws + OFF_Y3);
    float* genr  = (float*)(ws + OFF_GENR);

    hipMemsetAsync(d_ws, 0, 640, stream);

    k_conv1<<<512, 256, 0, stream>>>(gather, w1, b1, y1, sums);
    k_fused2<<<MM * F2_NCH, 256, 0, stream>>>(y1, sums, g1, be1, w2, b2, y2, sums);
    k_conv3<<<198, 256, 0, stream>>>(y2, sums, g2, be2, w3, b3, y3, sums);
    k_vintgenr<<<MM, 256, 0, stream>>>(cv, VMM, y3, sums, g3, be3, vint, genr);
    k_mixA<<<BSZ * (RHN / MC_TH), 256, 0, stream>>>(genr, vint, wf, bf, sums);
    k_mixB<<<BSZ * (RHN / MC_TH), 256, 0, stream>>>(genr, vint, wf, bf, sums, gf, bef, out);
}